// Round 2
// baseline (49.882 us; speedup 1.0000x reference)
//
#include <hip/hip_runtime.h>

#define HH 128
#define WW 192
#define CIN 8
#define NPARAM 169
#define HW (HH * WW)
// param layout: w0[8][10] @0, w1[8][8] @80, w2[8] @144, b0[8] @152, b1[8] @160, b2 @168

__global__ __launch_bounds__(256, 4) void dmh_fused_kernel(
    const float* __restrict__ mask_feats,   // (4,8,128,192)
    const float* __restrict__ params,       // (128,169)
    const float* __restrict__ locs,         // (128,2)
    const float* __restrict__ soi,          // (5,)
    const int*   __restrict__ im_inds,      // (128,)
    const int*   __restrict__ fpn_levels,   // (128,)
    const int*   __restrict__ stride_p,     // scalar (=8)
    float*       __restrict__ out)          // (128,1,256,384)
{
    const int tid = threadIdx.x;
    const int c0 = blockIdx.x * 64;   // source col tile origin
    const int r0 = blockIdx.y * 32;   // source row tile origin
    const int n  = blockIdx.z;        // instance

    __shared__ float tile[33 * 66];   // 33 rows x 65 cols (stride 66)

    // Uniform (wave-invariant) weight pointer -> compiler emits s_load;
    // FMAs consume weights straight from SGPRs (no LDS staging at all).
    const float* __restrict__ P = params + (size_t)n * NPARAM;

    const int   stride = *stride_p;                 // 8
    const float half   = 0.5f * (float)stride;      // 4.0
    const float locx = locs[2 * n + 0];
    const float locy = locs[2 * n + 1];
    const int   lvl  = fpn_levels[n];
    const float inv  = 1.0f / soi[lvl];
    const int   im   = im_inds[n];
    const float* fb  = mask_feats + (size_t)im * CIN * HW;

    // ---------- phase 1: per-pixel MLP over the 33x65 halo tile ----------
    int   foff[9], taddr[9];
    float rx[9], ry[9];
    #pragma unroll
    for (int k = 0; k < 9; ++k) {
        int idx = tid + k * 256; if (idx > 2144) idx = 2144;
        int r = idx / 65, c = idx - r * 65;
        taddr[k] = r * 66 + c;
        int rr = r0 - 1 + r; rr = rr < 0 ? 0 : (rr > HH - 1 ? HH - 1 : rr);
        int cc = c0 - 1 + c; cc = cc < 0 ? 0 : (cc > WW - 1 ? WW - 1 : cc);
        foff[k] = rr * WW + cc;
        rx[k] = (locx - ((float)(cc * stride) + half)) * inv;
        ry[k] = (locy - ((float)(rr * stride) + half)) * inv;
    }

    // 3 chunks of 3 pixels: small live set -> high occupancy.
    #pragma unroll
    for (int cch = 0; cch < 3; ++cch) {
        const int k0 = cch * 3;
        float h1[8][3];
        #pragma unroll
        for (int o = 0; o < 8; ++o) {
            float w0x = P[o * 10 + 0], w0y = P[o * 10 + 1], b = P[152 + o];
            #pragma unroll
            for (int j = 0; j < 3; ++j)
                h1[o][j] = fmaf(w0x, rx[k0 + j], fmaf(w0y, ry[k0 + j], b));
        }
        #pragma unroll
        for (int ch = 0; ch < 8; ++ch) {
            const float* f = fb + ch * HW;
            float x0 = f[foff[k0 + 0]];
            float x1 = f[foff[k0 + 1]];
            float x2 = f[foff[k0 + 2]];
            #pragma unroll
            for (int o = 0; o < 8; ++o) {
                float w = P[o * 10 + 2 + ch];
                h1[o][0] = fmaf(w, x0, h1[o][0]);
                h1[o][1] = fmaf(w, x1, h1[o][1]);
                h1[o][2] = fmaf(w, x2, h1[o][2]);
            }
        }
        float acc[8][3];
        #pragma unroll
        for (int o = 0; o < 8; ++o) {
            float b = P[160 + o];
            acc[o][0] = b; acc[o][1] = b; acc[o][2] = b;
        }
        #pragma unroll
        for (int i = 0; i < 8; ++i) {
            float v0 = fmaxf(h1[i][0], 0.0f);
            float v1 = fmaxf(h1[i][1], 0.0f);
            float v2 = fmaxf(h1[i][2], 0.0f);
            #pragma unroll
            for (int o = 0; o < 8; ++o) {
                float w = P[80 + o * 8 + i];   // w1[o][i]
                acc[o][0] = fmaf(w, v0, acc[o][0]);
                acc[o][1] = fmaf(w, v1, acc[o][1]);
                acc[o][2] = fmaf(w, v2, acc[o][2]);
            }
        }
        float lg0 = P[168], lg1 = lg0, lg2 = lg0;
        #pragma unroll
        for (int o = 0; o < 8; ++o) {
            float w2 = P[144 + o];
            lg0 = fmaf(w2, fmaxf(acc[o][0], 0.0f), lg0);
            lg1 = fmaf(w2, fmaxf(acc[o][1], 0.0f), lg1);
            lg2 = fmaf(w2, fmaxf(acc[o][2], 0.0f), lg2);
        }
        #pragma unroll
        for (int j = 0; j < 3; ++j) {
            int idx = tid + (k0 + j) * 256;
            float lg = (j == 0) ? lg0 : ((j == 1) ? lg1 : lg2);
            if (idx <= 2144) tile[taddr[k0 + j]] = lg;
        }
    }
    __syncthreads();

    // ---------- phase 2: x2 aligned upsample -> 64x128 output tile ----------
    const int kx = tid & 31;          // 32 groups of 4 output cols
    const int g  = tid >> 5;          // 8 row groups
    float* ob = out + ((size_t)n * 256 + 2 * r0) * 384 + 2 * c0 + 4 * kx;
    #pragma unroll
    for (int yy = 0; yy < 8; ++yy) {
        int yt = g * 8 + yy;
        int i  = 2 * r0 + yt - 1;
        int rb = i >> 1;
        int fy = i & 1;
        float wy0 = fy ? 0.5f : 1.0f;
        float wy1 = fy ? 0.5f : 0.0f;
        int lr  = rb - r0 + 1;        // in [0,32]
        int lr2 = lr + fy;            // in [0,32]
        const float* ra = &tile[lr  * 66 + 2 * kx];
        const float* rc = &tile[lr2 * 66 + 2 * kx];
        float t0 = fmaf(wy1, rc[0], wy0 * ra[0]);
        float t1 = fmaf(wy1, rc[1], wy0 * ra[1]);
        float t2 = fmaf(wy1, rc[2], wy0 * ra[2]);
        float4 o4;
        o4.x = 0.5f * (t0 + t1);
        o4.y = t1;
        o4.z = 0.5f * (t1 + t2);
        o4.w = t2;
        *reinterpret_cast<float4*>(ob + (size_t)yt * 384) = o4;
    }
}

extern "C" void kernel_launch(void* const* d_in, const int* in_sizes, int n_in,
                              void* d_out, int out_size, void* d_ws, size_t ws_size,
                              hipStream_t stream) {
    const float* mask_feats = (const float*)d_in[0];
    const float* params     = (const float*)d_in[1];
    const float* locs       = (const float*)d_in[2];
    const float* soi        = (const float*)d_in[3];
    const int*   im_inds    = (const int*)d_in[4];
    const int*   fpn_levels = (const int*)d_in[5];
    const int*   stride_p   = (const int*)d_in[6];
    float* out = (float*)d_out;

    dim3 grid(WW / 64, HH / 32, 128);   // (3, 4, 128)
    dim3 block(256);
    dmh_fused_kernel<<<grid, block, 0, stream>>>(
        mask_feats, params, locs, soi, im_inds, fpn_levels, stride_p, out);
}

// Round 3
// 21.098 us; speedup vs baseline: 2.3643x; 2.3643x over previous
//
#include <hip/hip_runtime.h>

#define HH 128
#define WW 192
#define HW (HH * WW)

// Rearranged weight layout in LDS (all 8-wide rows 16B-aligned):
// [0..7]   w0x[o]        (= P[o*10+0])
// [8..15]  w0y[o]        (= P[o*10+1])
// [16..23] b0[o]         (= P[152+o])
// [24..87] w0t[ch][o]    (= P[o*10+2+ch])   8 rows of 8
// [88..151] w1t[i][o]    (= P[80+o*8+i])    8 rows of 8
// [152..159] w2[o]       (= P[144+o])
// [160..167] b1[o]       (= P[160+o])
// [168]     b2           (= P[168])

__device__ __forceinline__ float relu(float v) { return fmaxf(v, 0.0f); }

__global__ __launch_bounds__(512, 4) void dmh_kernel(
    const float* __restrict__ mask_feats,   // (4,8,128,192)
    const float* __restrict__ params,       // (128,169)
    const float* __restrict__ locs,         // (128,2)
    const float* __restrict__ soi,          // (5,)
    const int*   __restrict__ im_inds,      // (128,)
    const int*   __restrict__ fpn_levels,   // (128,)
    const int*   __restrict__ stride_p,     // scalar (=8)
    float*       __restrict__ out)          // (128,1,256,384)
{
    const int tid = threadIdx.x;
    const int c0 = blockIdx.x * 64;   // source col tile origin
    const int r0 = blockIdx.y * 32;   // source row tile origin
    const int n  = blockIdx.z;        // instance

    __shared__ float sW[176];
    __shared__ float tile[33 * 66];   // rows -1..31 -> 0..32, cols -1..63 -> 0..64

    // ---- stage + transpose weights into LDS (coalesced read, scattered write) ----
    if (tid < 169) {
        float v = params[(size_t)n * 169 + tid];
        int d;
        if (tid < 80)       { int o = tid / 10, r = tid - o * 10;
                              d = (r == 0) ? o : (r == 1) ? (8 + o) : (24 + (r - 2) * 8 + o); }
        else if (tid < 144) { int t = tid - 80, o = t >> 3, i = t & 7; d = 88 + i * 8 + o; }
        else if (tid < 152) d = 152 + (tid - 144);
        else if (tid < 160) d = 16 + (tid - 152);
        else if (tid < 168) d = 160 + (tid - 160);
        else                d = 168;
        sW[d] = v;
    }

    const int   stride = *stride_p;                 // 8
    const float half   = 0.5f * (float)stride;      // 4.0
    const float locx = locs[2 * n + 0];
    const float locy = locs[2 * n + 1];
    const float inv  = 1.0f / soi[fpn_levels[n]];
    const float* fb  = mask_feats + (size_t)im_inds[n] * 8 * HW;

    __syncthreads();

    // ---------- phase 1a: interior 32x64, 4 contiguous px per thread ----------
    {
        const int ir = tid >> 4;          // 0..31
        const int ic = (tid & 15) << 2;   // 0,4,...,60
        const int rr = r0 + ir, cc = c0 + ic;   // always in-bounds
        const float* fp = fb + rr * WW + cc;

        // all 8 channel loads issued before any use: one vmcnt wait total
        float4 xv[8];
        #pragma unroll
        for (int ch = 0; ch < 8; ++ch)
            xv[ch] = *reinterpret_cast<const float4*>(fp + ch * HW);

        const float rxd = -(float)stride * inv;
        float rx[4];
        rx[0] = (locx - (float)(cc * stride) - half) * inv;
        rx[1] = rx[0] + rxd; rx[2] = rx[1] + rxd; rx[3] = rx[2] + rxd;
        const float ry = (locy - (float)(rr * stride) - half) * inv;

        float h[8][4];
        #pragma unroll
        for (int o = 0; o < 8; ++o) {
            float t  = fmaf(sW[8 + o], ry, sW[16 + o]);
            float wx = sW[o];
            #pragma unroll
            for (int j = 0; j < 4; ++j) h[o][j] = fmaf(wx, rx[j], t);
        }
        #pragma unroll
        for (int ch = 0; ch < 8; ++ch) {
            float4 wlo = *reinterpret_cast<const float4*>(&sW[24 + ch * 8]);
            float4 whi = *reinterpret_cast<const float4*>(&sW[28 + ch * 8]);
            float wv[8] = {wlo.x, wlo.y, wlo.z, wlo.w, whi.x, whi.y, whi.z, whi.w};
            float xj[4] = {xv[ch].x, xv[ch].y, xv[ch].z, xv[ch].w};
            #pragma unroll
            for (int o = 0; o < 8; ++o)
                #pragma unroll
                for (int j = 0; j < 4; ++j) h[o][j] = fmaf(wv[o], xj[j], h[o][j]);
        }

        float a[8][4];
        #pragma unroll
        for (int o = 0; o < 8; ++o) {
            float b = sW[160 + o];
            #pragma unroll
            for (int j = 0; j < 4; ++j) a[o][j] = b;
        }
        #pragma unroll
        for (int i = 0; i < 8; ++i) {
            float4 wlo = *reinterpret_cast<const float4*>(&sW[88 + i * 8]);
            float4 whi = *reinterpret_cast<const float4*>(&sW[92 + i * 8]);
            float wv[8] = {wlo.x, wlo.y, wlo.z, wlo.w, whi.x, whi.y, whi.z, whi.w};
            float vj[4] = {relu(h[i][0]), relu(h[i][1]), relu(h[i][2]), relu(h[i][3])};
            #pragma unroll
            for (int o = 0; o < 8; ++o)
                #pragma unroll
                for (int j = 0; j < 4; ++j) a[o][j] = fmaf(wv[o], vj[j], a[o][j]);
        }

        float b2v = sW[168];
        float lg[4] = {b2v, b2v, b2v, b2v};
        #pragma unroll
        for (int o = 0; o < 8; ++o) {
            float w2 = sW[152 + o];
            #pragma unroll
            for (int j = 0; j < 4; ++j) lg[j] = fmaf(w2, relu(a[o][j]), lg[j]);
        }
        #pragma unroll
        for (int j = 0; j < 4; ++j)
            tile[(ir + 1) * 66 + ic + 1 + j] = lg[j];
    }

    // ---------- phase 1b: 97 halo px (row -1, col -1), scalar ----------
    if (tid < 97) {
        int r, c;
        if (tid < 65) { r = -1; c = tid - 1; }      // row -1, cols -1..63
        else          { r = tid - 65; c = -1; }     // rows 0..31, col -1
        int rr = min(max(r0 + r, 0), HH - 1);
        int cc = min(max(c0 + c, 0), WW - 1);
        const float* fp = fb + rr * WW + cc;
        float rx  = (locx - (float)(cc * stride) - half) * inv;
        float ry2 = (locy - (float)(rr * stride) - half) * inv;
        float hh[8];
        #pragma unroll
        for (int o = 0; o < 8; ++o)
            hh[o] = fmaf(sW[o], rx, fmaf(sW[8 + o], ry2, sW[16 + o]));
        #pragma unroll
        for (int ch = 0; ch < 8; ++ch) {
            float x = fp[ch * HW];
            #pragma unroll
            for (int o = 0; o < 8; ++o) hh[o] = fmaf(sW[24 + ch * 8 + o], x, hh[o]);
        }
        float aa[8];
        #pragma unroll
        for (int o = 0; o < 8; ++o) aa[o] = sW[160 + o];
        #pragma unroll
        for (int i = 0; i < 8; ++i) {
            float v = relu(hh[i]);
            #pragma unroll
            for (int o = 0; o < 8; ++o) aa[o] = fmaf(sW[88 + i * 8 + o], v, aa[o]);
        }
        float lg = sW[168];
        #pragma unroll
        for (int o = 0; o < 8; ++o) lg = fmaf(sW[152 + o], relu(aa[o]), lg);
        tile[(r + 1) * 66 + (c + 1)] = lg;
    }
    __syncthreads();

    // ---------- phase 2: x2 aligned upsample -> 64x128 output tile ----------
    const int kx = tid & 31;          // 32 groups of 4 output cols
    const int ky = tid >> 5;          // 16 row groups of 4 rows
    float* ob = out + ((size_t)n * 256 + 2 * r0) * 384 + 2 * c0 + 4 * kx;
    #pragma unroll
    for (int yy = 0; yy < 4; ++yy) {
        int yt = ky * 4 + yy;         // 0..63
        int i  = 2 * r0 + yt - 1;
        int rb = i >> 1;              // arithmetic shift handles i=-1
        int fy = i & 1;
        float wy0 = fy ? 0.5f : 1.0f;
        float wy1 = fy ? 0.5f : 0.0f;
        int lr  = rb - r0 + 1;        // in [0,32]
        int lr2 = lr + fy;            // in [0,32]
        const float* ra = &tile[lr  * 66 + 2 * kx];
        const float* rc = &tile[lr2 * 66 + 2 * kx];
        float t0 = fmaf(wy1, rc[0], wy0 * ra[0]);
        float t1 = fmaf(wy1, rc[1], wy0 * ra[1]);
        float t2 = fmaf(wy1, rc[2], wy0 * ra[2]);
        float4 o4;
        o4.x = 0.5f * (t0 + t1);
        o4.y = t1;
        o4.z = 0.5f * (t1 + t2);
        o4.w = t2;
        *reinterpret_cast<float4*>(ob + (size_t)yt * 384) = o4;
    }
}

extern "C" void kernel_launch(void* const* d_in, const int* in_sizes, int n_in,
                              void* d_out, int out_size, void* d_ws, size_t ws_size,
                              hipStream_t stream) {
    const float* mask_feats = (const float*)d_in[0];
    const float* params     = (const float*)d_in[1];
    const float* locs       = (const float*)d_in[2];
    const float* soi        = (const float*)d_in[3];
    const int*   im_inds    = (const int*)d_in[4];
    const int*   fpn_levels = (const int*)d_in[5];
    const int*   stride_p   = (const int*)d_in[6];
    float* out = (float*)d_out;

    dim3 grid(WW / 64, HH / 32, 128);   // (3, 4, 128)
    dim3 block(512);
    dmh_kernel<<<grid, block, 0, stream>>>(
        mask_feats, params, locs, soi, im_inds, fpn_levels, stride_p, out);
}